// Round 5
// baseline (268.777 us; speedup 1.0000x reference)
//
#include <hip/hip_runtime.h>

// x [B=8, H=224, W=224, D=8, C=8] fp32, out [8, 8, 8, 10] fp32.
// lane = w-column (55 owned + 9 halo), 2 channels/lane (float2 loads),
// horizontal neighbor via DPP wave_shl:1 (zero DS ops in hot loop).
// Round-5 deltas vs the 102us round-3 kernel (which was latency-bound at
// 5 blocks/CU, 1-row prefetch, 26% issue efficiency):
//   - STRIP 56->28: grid 1280->2560 blocks (8 resident blocks/CU, ~2x waves)
//   - 2-deep row prefetch (n1/n2, +4 regs) with scalar-clamped row index:
//     load->use gap ~380cy of own work, per-row rend-branch gone
//   - warm/tail rows fully unrolled, guards compile-time (template <WI,TI>)
// Round-1/2/4 lesson held: live state stays ~54 floats (VGPR ~60), NO deep
// per-row buffers -- round 4's 4-row group spilled (WRITE_SIZE 3.2->92MB).
#define BB 8
#define HH 224
#define WW 224
#define DCH 64
#define NS 10
#define SEG 55    // owned output columns per wave (lanes 55..63 = halo)
#define NSEG 5
#define STRIP 28  // output rows per strip
#define NHS 8     // 8*28 = 224
#define NCG 8     // 8 channel-groups of 8 ch per block (wave = 2 ch)
#define NBLK (BB * NCG * NSEG * NHS) // 2560 = 8 XCDs * 320 (one batch per XCD)
#define RST (WW * DCH)               // floats per input row

__global__ void zero_kernel(float* out, int n) {
    int i = blockIdx.x * blockDim.x + threadIdx.x;
    if (i < n) out[i] = 0.0f;
}

__global__ void finalize_kernel(float* out, int n) {
    int i = blockIdx.x * blockDim.x + threadIdx.x;
    if (i < n) out[i] = fmaxf(out[i], 0.0f) + 1.0f;
}

// lane i <- lane i+1 (wave_shl:1 = 0x130), lane 63 reads 0 (bound_ctrl).
// Verified by rounds 3/4 refchecks; folds into v_max_f32_dpp.
__device__ __forceinline__ float dpp_shl1(float v) {
    return __int_as_float(__builtin_amdgcn_mov_dpp(__float_as_int(v), 0x130, 0xF, 0xF, true));
}

// One row through the 2x2 max cascade (round-3 semantics).
// WI: warm row index 0..8 (guard lv <= WI-1), -1 = not warm.
// TI: tail row index 0..8 (guard lv >= TI, scale 1 off), -1 = not tail.
template<int WI, int TI>
__device__ __forceinline__ void row_body(const float (&m)[NS], float (&cp)[2],
                                         float (&prev)[NS - 1][2], float (&acc)[NS][2]) {
    if (TI < 0) { // scale 1: raw row is an in-strip output row
        acc[0][0] = fmaf(cp[0], m[0], acc[0][0]);
        acc[0][1] = fmaf(cp[1], m[0], acc[0][1]);
    }
#pragma unroll
    for (int lv = 0; lv < NS - 1; ++lv) { // level lv -> scale lv+2
        float vm0 = fmaxf(prev[lv][0], cp[0]); // vertical max (rows h-1, h)
        float vm1 = fmaxf(prev[lv][1], cp[1]);
        prev[lv][0] = cp[0];                   // rotate history
        prev[lv][1] = cp[1];
        cp[0] = fmaxf(vm0, dpp_shl1(vm0));     // horizontal max (cols j, j+1)
        cp[1] = fmaxf(vm1, dpp_shl1(vm1));
        bool on = true;                        // compile-time in warm/tail
        if (WI >= 0) on = (WI >= lv + 1);      // r = h-lv-1 >= row0
        if (TI >= 0) on = (lv >= TI);          // r < row0 + STRIP
        if (on) {
            acc[lv + 1][0] = fmaf(cp[0], m[lv + 1], acc[lv + 1][0]);
            acc[lv + 1][1] = fmaf(cp[1], m[lv + 1], acc[lv + 1][1]);
        }
    }
}

__global__ __launch_bounds__(256, 6) void pool_kernel(const float* __restrict__ x,
                                                      float* __restrict__ out) {
    // Bijective XCD swizzle: 2560 = 8*320 -> XCD k owns exactly batch k
    // (halo/channel-group re-reads and output atomics stay in one L2).
    const int phys = blockIdx.x;
    const int logical = (phys & 7) * (NBLK / 8) + (phys >> 3);
    const int b  = logical / (NCG * NSEG * NHS);
    const int r  = logical % (NCG * NSEG * NHS);
    const int cg = r & 7;
    const int ws = (r >> 3) % NSEG;
    const int hs = (r >> 3) / NSEG;

    const int wv   = threadIdx.x >> 6;
    const int lane = threadIdx.x & 63;
    const int ch   = cg * 8 + wv * 2;
    const int col  = ws * SEG + lane;
    const int row0 = hs * STRIP;
    const int R    = min(STRIP + NS - 1, HH - row0); // 37, or 28 (bottom strip)

    float m[NS]; // per-scale column-ownership mask (0/1, applied via fma)
#pragma unroll
    for (int s = 1; s <= NS; ++s)
        m[s - 1] = (lane < SEG && col <= WW - s) ? 1.0f : 0.0f;

    float prev[NS - 1][2], acc[NS][2], cp[2], n1[2], n2[2];
#pragma unroll
    for (int lv = 0; lv < NS - 1; ++lv) { prev[lv][0] = 0.0f; prev[lv][1] = 0.0f; }
#pragma unroll
    for (int s = 0; s < NS; ++s) { acc[s][0] = 0.0f; acc[s][1] = 0.0f; }

    // Column clamp (identity for interior waves): loads always valid; masked
    // lanes' garbage stays finite so fma(g, 0, acc) is exact (rounds 3/4 ok).
    const int colc = min(col, WW - 1);
    const float* px0 = x + ((size_t)(b * HH + row0) * WW + colc) * DCH + ch;

    { const float2 t = *(const float2*)px0;                    n1[0] = t.x; n1[1] = t.y; }
    { const float2 t = *(const float2*)(px0 + (size_t)RST);    n2[0] = t.x; n2[1] = t.y; }

    // Warm rows i=0..8: loads at i+2 <= 10 < R always; guards compile-time.
#define WSTEP(i)                                                             \
    {                                                                        \
        cp[0] = n1[0]; cp[1] = n1[1]; n1[0] = n2[0]; n1[1] = n2[1];          \
        const float2 t2 = *(const float2*)(px0 + (size_t)((i) + 2) * RST);   \
        n2[0] = t2.x; n2[1] = t2.y;                                          \
        row_body<(i), -1>(m, cp, prev, acc);                                 \
    }
    WSTEP(0) WSTEP(1) WSTEP(2) WSTEP(3) WSTEP(4)
    WSTEP(5) WSTEP(6) WSTEP(7) WSTEP(8)
#undef WSTEP

    // Steady rows: guard-free bodies; prefetch row clamped scalar-side.
    {
        const int rel_end = min(STRIP, R); // 28 (full) or 28 (bottom) -> 19 rows
#pragma unroll 2
        for (int rel = NS - 1; rel < rel_end; ++rel) {
            cp[0] = n1[0]; cp[1] = n1[1]; n1[0] = n2[0]; n1[1] = n2[1];
            const int rr = min(rel + 2, R - 1);
            const float2 t2 = *(const float2*)(px0 + (size_t)rr * RST);
            n2[0] = t2.x; n2[1] = t2.y;
            row_body<-1, -1>(m, cp, prev, acc);
        }
    }

    // Tail rows (full strips only) i=0..8: loads clamp to R-1=36; trailing
    // redundant loads of row 36 are dead (n2 dies) and L1-hot anyway.
    if (R == STRIP + NS - 1) {
#define TSTEP(i)                                                             \
    {                                                                        \
        cp[0] = n1[0]; cp[1] = n1[1]; n1[0] = n2[0]; n1[1] = n2[1];          \
        const int rr = ((i) + STRIP + 2 < STRIP + NS - 1) ? (i) + STRIP + 2  \
                                                          : STRIP + NS - 2;  \
        const float2 t2 = *(const float2*)(px0 + (size_t)rr * RST);          \
        n2[0] = t2.x; n2[1] = t2.y;                                          \
        row_body<-1, (i)>(m, cp, prev, acc);                                 \
    }
        TSTEP(0) TSTEP(1) TSTEP(2) TSTEP(3) TSTEP(4)
        TSTEP(5) TSTEP(6) TSTEP(7) TSTEP(8)
#undef TSTEP
    }

    // Wave butterfly, then lane 0 atomics 20 partials (one per scale/channel).
#pragma unroll
    for (int s = 0; s < NS; ++s)
#pragma unroll
        for (int c = 0; c < 2; ++c) {
            float v = acc[s][c];
#pragma unroll
            for (int off = 32; off > 0; off >>= 1) v += __shfl_xor(v, off);
            if (lane == 0) atomicAdd(&out[((size_t)b * DCH + ch + c) * NS + s], v);
        }
}

extern "C" void kernel_launch(void* const* d_in, const int* in_sizes, int n_in,
                              void* d_out, int out_size, void* d_ws, size_t ws_size,
                              hipStream_t stream) {
    const float* x = (const float*)d_in[0];
    float* out = (float*)d_out;
    const int nblk = (out_size + 255) / 256;
    zero_kernel<<<nblk, 256, 0, stream>>>(out, out_size);
    pool_kernel<<<NBLK, 256, 0, stream>>>(x, out);
    finalize_kernel<<<nblk, 256, 0, stream>>>(out, out_size);
}

// Round 6
// 206.538 us; speedup vs baseline: 1.3013x; 1.3013x over previous
//
#include <hip/hip_runtime.h>

// x [B=8, H=224, W=224, D=8, C=8] fp32, out [8, 8, 8, 10] fp32.
// Layout: lane = w-column (55 owned + 9 halo per wave), 2 channels/lane
// (float2 loads). Horizontal neighbor (col+1) via DPP wave_shl:1 -- zero
// cross-lane DS ops in the hot loop.
// ROUND-6: exact round-3 source (102us, VGPR 48, no spill) with ONE knob:
// STRIP 56->28 (grid 1280->2560, 5->10 blocks/CU) to lift occupancy 46%->~80%.
// Hard-won allocator lessons (rounds 1/2/4/5): loop-based row pipeline with
// runtime uniform guards and 1-deep prefetch is the ONLY shape hipcc keeps
// in 48 VGPRs. Full warm/tail unrolls or >=2-row buffers -> acc/prev spill
// (WRITE_SIZE 92MB/169MB fingerprints). DO NOT unroll the row phases.
#define BB 8
#define HH 224
#define WW 224
#define DCH 64
#define NS 10
#define SEG 55    // owned output columns per wave (lanes 55..63 = halo)
#define NSEG 5    // 5*55 = 275 >= 224 (last segment ragged)
#define STRIP 28  // output rows per h-strip  (round 3 had 56)
#define NHS 8     // 8*28 = 224
#define NCG 8     // 8 channel-groups of 8 ch per block (wave = 2 ch)
#define NBLK (BB * NCG * NSEG * NHS) // 2560 = 8 XCDs * 320 (one batch per XCD)

__global__ void zero_kernel(float* out, int n) {
    int i = blockIdx.x * blockDim.x + threadIdx.x;
    if (i < n) out[i] = 0.0f;
}

__global__ void finalize_kernel(float* out, int n) {
    int i = blockIdx.x * blockDim.x + threadIdx.x;
    if (i < n) out[i] = fmaxf(out[i], 0.0f) + 1.0f;
}

// lane i <- lane i+1, full-wave shift (DPP WAVE_SHL1 = 0x130). Lane 63 gets 0
// (bound_ctrl) -- only ever feeds halo/masked outputs.
__device__ __forceinline__ float dpp_shl1(float v) {
    return __int_as_float(__builtin_amdgcn_mov_dpp(__float_as_int(v), 0x130, 0xF, 0xF, true));
}

// One input row through the 2x2 max cascade. PHASE: 0 = warmup (guard r>=row0),
// 1 = steady (no guards), 2 = tail (guard r<row0+STRIP).
template<int PHASE>
__device__ __forceinline__ void row_body(int h, int row0, const float (&m)[NS],
                                         float (&cp)[2], float (&prev)[NS - 1][2],
                                         float (&acc)[NS][2]) {
    if (PHASE != 2) { // scale 1: raw row (warmup/steady always have h in strip)
        acc[0][0] = fmaf(cp[0], m[0], acc[0][0]);
        acc[0][1] = fmaf(cp[1], m[0], acc[0][1]);
    }
#pragma unroll
    for (int lv = 0; lv < NS - 1; ++lv) { // level lv -> scale lv+2, out row h-lv-1
        float vm0 = fmaxf(prev[lv][0], cp[0]); // vertical max (rows h-1, h)
        float vm1 = fmaxf(prev[lv][1], cp[1]);
        prev[lv][0] = cp[0];                   // rotate history
        prev[lv][1] = cp[1];
        cp[0] = fmaxf(vm0, dpp_shl1(vm0));     // horizontal max (cols j, j+1)
        cp[1] = fmaxf(vm1, dpp_shl1(vm1));
        bool on = true; // uniform (h, row0 scalar) -> s_cmp + s_cbranch
        if (PHASE == 0) on = (h - lv - 1) >= row0;
        if (PHASE == 2) on = (h - lv - 1) < row0 + STRIP;
        if (on) {
            acc[lv + 1][0] = fmaf(cp[0], m[lv + 1], acc[lv + 1][0]);
            acc[lv + 1][1] = fmaf(cp[1], m[lv + 1], acc[lv + 1][1]);
        }
    }
}

__global__ __launch_bounds__(256, 4) void pool_kernel(const float* __restrict__ x,
                                                      float* __restrict__ out) {
    // Bijective XCD swizzle: 2560 = 8*320 -> XCD k owns batch k (halo re-reads
    // and atomics stay in one L2). Within a batch, the 8 channel-group blocks
    // of one (hs,ws) tile are adjacent -> they re-read the same x lines (L2 hit).
    const int phys = blockIdx.x;
    const int logical = (phys & 7) * (NBLK / 8) + (phys >> 3);
    const int b = logical / (NCG * NSEG * NHS);
    const int r = logical % (NCG * NSEG * NHS);
    const int cg = r & 7;
    const int ws = (r >> 3) % NSEG;
    const int hs = (r >> 3) / NSEG;

    const int wv   = threadIdx.x >> 6;
    const int lane = threadIdx.x & 63;
    const int ch   = cg * 8 + wv * 2;      // 2 channels per lane, 8 per block
    const int col  = ws * SEG + lane;
    const int row0 = hs * STRIP;
    const int rend = min(row0 + STRIP + NS - 1, HH);

    float m[NS]; // per-scale column ownership (0/1, used via fma)
#pragma unroll
    for (int s = 1; s <= NS; ++s)
        m[s - 1] = (lane < SEG && col <= WW - s) ? 1.0f : 0.0f;

    float prev[NS - 1][2], acc[NS][2], cp[2], nv[2];
#pragma unroll
    for (int lv = 0; lv < NS - 1; ++lv) { prev[lv][0] = 0.0f; prev[lv][1] = 0.0f; }
#pragma unroll
    for (int s = 0; s < NS; ++s) { acc[s][0] = 0.0f; acc[s][1] = 0.0f; }
    nv[0] = 0.0f; nv[1] = 0.0f;

    const bool colok = (col < WW);
    const float* px = x + (((size_t)(b * HH + row0) * WW + col) * DCH + ch);
    const ptrdiff_t rstride = (ptrdiff_t)WW * DCH;

    if (colok) { float2 t = *(const float2*)px; nv[0] = t.x; nv[1] = t.y; }

#define ROW_STEP(P)                                                          \
    {                                                                        \
        cp[0] = nv[0]; cp[1] = nv[1];                                        \
        if (h + 1 < rend) { /* uniform: prefetch next row under the VALU */  \
            px += rstride;                                                   \
            if (colok) { float2 t = *(const float2*)px; nv[0] = t.x; nv[1] = t.y; } \
        }                                                                    \
        row_body<P>(h, row0, m, cp, prev, acc);                              \
    }

    int h = row0;
    const int warm_end = row0 + NS - 1;                // 9 warmup rows
    for (; h < warm_end; ++h) ROW_STEP(0)
    const int steady_end = min(row0 + STRIP, rend);    // 19 branch-free rows
    for (; h < steady_end; ++h) ROW_STEP(1)
    for (; h < rend; ++h) ROW_STEP(2)                  // <=9 tail rows
#undef ROW_STEP

    // Wave butterfly reduction (one-time), then lane 0 atomics 20 partials.
#pragma unroll
    for (int s = 0; s < NS; ++s) {
#pragma unroll
        for (int c = 0; c < 2; ++c) {
            float v = acc[s][c];
#pragma unroll
            for (int off = 32; off > 0; off >>= 1) v += __shfl_xor(v, off);
            if (lane == 0) atomicAdd(&out[((size_t)b * DCH + ch + c) * NS + s], v);
        }
    }
}

extern "C" void kernel_launch(void* const* d_in, const int* in_sizes, int n_in,
                              void* d_out, int out_size, void* d_ws, size_t ws_size,
                              hipStream_t stream) {
    const float* x = (const float*)d_in[0];
    float* out = (float*)d_out;
    const int nblk = (out_size + 255) / 256;
    zero_kernel<<<nblk, 256, 0, stream>>>(out, out_size);
    pool_kernel<<<NBLK, 256, 0, stream>>>(x, out);
    finalize_kernel<<<nblk, 256, 0, stream>>>(out, out_size);
}

// Round 7
// 192.385 us; speedup vs baseline: 1.3971x; 1.0736x over previous
//
#include <hip/hip_runtime.h>

// x [B=8, H=224, W=224, D=8, C=8] fp32, out [8, 8, 8, 10] fp32.
// Compute layout (proven, rounds 3/6): lane = w-column (55 owned + 9 halo),
// 2 channels/lane, DPP wave_shl:1 for the col+1 neighbor, loop-based phase
// guards (NEVER unroll the row phases: rounds 4/5 spilled -> WRITE_SIZE 92/169MB).
// ROUND-7: fix the gather-bound load path. Old: each lane loaded 8B at 256B
// stride -> 64 lines per wave-load, x4 waves re-gathering the same lines =
// 256 line-transactions/block-row through the TA (~40-80us of address-path
// serialization; explains round-6's null result: more waves share one TA).
// New: block stages each row's 64col x 8ch tile (2KB) into LDS coalesced
// (thread t -> col t>>2, chpair t&3: 16 lines/wave, tile loaded ONCE), then
// compute waves ds_read their float2 (2-way bank access = free). One barrier
// per row via 1-row LDS pipeline; global load issued a full row ahead.
#define BB 8
#define HH 224
#define WW 224
#define DCH 64
#define NS 10
#define SEG 55    // owned output columns per wave (lanes 55..63 = halo)
#define NSEG 5    // 5*55 = 275 >= 224 (last segment ragged)
#define STRIP 28  // output rows per h-strip
#define NHS 8     // 8*28 = 224
#define NCG 8     // 8 channel-groups of 8 ch per block (wave = 2 ch)
#define NBLK (BB * NCG * NSEG * NHS) // 2560 = 8 XCDs * 320 (one batch per XCD)
#define PS 72                        // LDS plane stride in floats (64 + 8 pad)
#define LDSBUF (8 * PS)              // floats per row buffer (8 ch planes)

__global__ void zero_kernel(float* out, int n) {
    int i = blockIdx.x * blockDim.x + threadIdx.x;
    if (i < n) out[i] = 0.0f;
}

__global__ void finalize_kernel(float* out, int n) {
    int i = blockIdx.x * blockDim.x + threadIdx.x;
    if (i < n) out[i] = fmaxf(out[i], 0.0f) + 1.0f;
}

// lane i <- lane i+1, full-wave shift (DPP WAVE_SHL1 = 0x130). Lane 63 gets 0
// (bound_ctrl) -- only ever feeds halo/masked outputs. Verified r3/r6.
__device__ __forceinline__ float dpp_shl1(float v) {
    return __int_as_float(__builtin_amdgcn_mov_dpp(__float_as_int(v), 0x130, 0xF, 0xF, true));
}

// One input row through the 2x2 max cascade (byte-identical to round 6).
// PHASE: 0 = warmup (guard r>=row0), 1 = steady, 2 = tail (guard r<row0+STRIP).
template<int PHASE>
__device__ __forceinline__ void row_body(int h, int row0, const float (&m)[NS],
                                         float (&cp)[2], float (&prev)[NS - 1][2],
                                         float (&acc)[NS][2]) {
    if (PHASE != 2) { // scale 1: raw row
        acc[0][0] = fmaf(cp[0], m[0], acc[0][0]);
        acc[0][1] = fmaf(cp[1], m[0], acc[0][1]);
    }
#pragma unroll
    for (int lv = 0; lv < NS - 1; ++lv) { // level lv -> scale lv+2, out row h-lv-1
        float vm0 = fmaxf(prev[lv][0], cp[0]); // vertical max (rows h-1, h)
        float vm1 = fmaxf(prev[lv][1], cp[1]);
        prev[lv][0] = cp[0];                   // rotate history
        prev[lv][1] = cp[1];
        cp[0] = fmaxf(vm0, dpp_shl1(vm0));     // horizontal max (cols j, j+1)
        cp[1] = fmaxf(vm1, dpp_shl1(vm1));
        bool on = true; // uniform -> s_cmp + s_cbranch
        if (PHASE == 0) on = (h - lv - 1) >= row0;
        if (PHASE == 2) on = (h - lv - 1) < row0 + STRIP;
        if (on) {
            acc[lv + 1][0] = fmaf(cp[0], m[lv + 1], acc[lv + 1][0]);
            acc[lv + 1][1] = fmaf(cp[1], m[lv + 1], acc[lv + 1][1]);
        }
    }
}

__global__ __launch_bounds__(256, 4) void pool_kernel(const float* __restrict__ x,
                                                      float* __restrict__ out) {
    __shared__ float lds[2 * LDSBUF]; // 4608 B: double-buffered row tile

    // Bijective XCD swizzle: 2560 = 8*320 -> XCD k owns batch k (tile re-reads
    // across channel-group blocks and the output atomics stay in one L2).
    const int phys = blockIdx.x;
    const int logical = (phys & 7) * (NBLK / 8) + (phys >> 3);
    const int b = logical / (NCG * NSEG * NHS);
    const int r = logical % (NCG * NSEG * NHS);
    const int cg = r & 7;
    const int ws = (r >> 3) % NSEG;
    const int hs = (r >> 3) / NSEG;

    const int wv   = threadIdx.x >> 6;
    const int lane = threadIdx.x & 63;
    const int ch   = cg * 8 + wv * 2;      // this wave's 2 channels
    const int col  = ws * SEG + lane;      // this lane's column (compute view)
    const int row0 = hs * STRIP;
    const int rend = min(row0 + STRIP + NS - 1, HH); // 37 rows (28 bottom strip)

    float m[NS]; // per-scale column ownership (0/1, used via fma)
#pragma unroll
    for (int s = 1; s <= NS; ++s)
        m[s - 1] = (lane < SEG && col <= WW - s) ? 1.0f : 0.0f;

    float prev[NS - 1][2], acc[NS][2], cp[2];
#pragma unroll
    for (int lv = 0; lv < NS - 1; ++lv) { prev[lv][0] = 0.0f; prev[lv][1] = 0.0f; }
#pragma unroll
    for (int s = 0; s < NS; ++s) { acc[s][0] = 0.0f; acc[s][1] = 0.0f; }

    // ---- Stager mapping (all 256 threads): coalesced 8B chunks ----
    // thread t -> column t>>2, channel-pair t&3: wave covers 16 cols x 32B
    // slices = 16 line-touches (vs 64 for the old per-lane gather).
    const int scol = threadIdx.x >> 2;
    const int q    = threadIdx.x & 3;
    const int gcol = min(ws * SEG + scol, WW - 1); // right-edge clamp (masked later)
    const float* sp = x + (((size_t)(b * HH + row0) * WW + gcol) * DCH + cg * 8 + q * 2);
    const ptrdiff_t rstride = (ptrdiff_t)WW * DCH;

    // LDS indices. Write: planes 2q, 2q+1 at col scol. Read: planes 2wv, 2wv+1
    // at col lane. PS=72 pad makes both exactly 2-way bank accesses (free).
    const int wbase = (2 * q) * PS + scol;
    const int rbase = (2 * wv) * PS + lane;

    // Prologue: row0 -> buf0; g <- row row0+1 (row0+1 < rend always).
    { float2 t0 = *(const float2*)sp;
      lds[wbase] = t0.x; lds[wbase + PS] = t0.y; }
    sp += rstride;
    float2 g = *(const float2*)sp;
    int sb = 0; // current read-buffer base (0 or LDSBUF)

    // Invariant at top of iter h: lds[sb..] = row h, g = row h+1.
    // One barrier/row: orders last iter's writes (row h into sb) before reads,
    // and last iter's reads (sb^) before this iter's writes into sb^.
#define ROW_STEP(P)                                                           \
    {                                                                         \
        __syncthreads();                                                      \
        const int so = sb ^ LDSBUF;                                           \
        lds[so + wbase] = g.x; lds[so + wbase + PS] = g.y; /* row h+1 */      \
        if (h + 2 < rend) { sp += rstride; g = *(const float2*)sp; }          \
        cp[0] = lds[sb + rbase]; cp[1] = lds[sb + rbase + PS]; /* row h */    \
        row_body<P>(h, row0, m, cp, prev, acc);                               \
        sb = so;                                                              \
    }

    int h = row0;
    const int warm_end = row0 + NS - 1;                // 9 warmup rows
    for (; h < warm_end; ++h) ROW_STEP(0)
    const int steady_end = min(row0 + STRIP, rend);    // 19 branch-free rows
    for (; h < steady_end; ++h) ROW_STEP(1)
    for (; h < rend; ++h) ROW_STEP(2)                  // <=9 tail rows
#undef ROW_STEP

    // Wave butterfly reduction (one-time), then lane 0 atomics 20 partials.
#pragma unroll
    for (int s = 0; s < NS; ++s) {
#pragma unroll
        for (int c = 0; c < 2; ++c) {
            float v = acc[s][c];
#pragma unroll
            for (int off = 32; off > 0; off >>= 1) v += __shfl_xor(v, off);
            if (lane == 0) atomicAdd(&out[((size_t)b * DCH + ch + c) * NS + s], v);
        }
    }
}

extern "C" void kernel_launch(void* const* d_in, const int* in_sizes, int n_in,
                              void* d_out, int out_size, void* d_ws, size_t ws_size,
                              hipStream_t stream) {
    const float* x = (const float*)d_in[0];
    float* out = (float*)d_out;
    const int nblk = (out_size + 255) / 256;
    zero_kernel<<<nblk, 256, 0, stream>>>(out, out_size);
    pool_kernel<<<NBLK, 256, 0, stream>>>(x, out);
    finalize_kernel<<<nblk, 256, 0, stream>>>(out, out_size);
}